// Round 14
// baseline (467.124 us; speedup 1.0000x reference)
//
#include <hip/hip_runtime.h>

#define N_NODES 50000
#define N_EDGES 800000
#define D 128
#define C_OUT 10
#define BN_EPS 1e-5f
#define CAP 64            // padded adjacency row capacity; P(deg>=63)~1e-17 (Poisson 16)
#define GEMM_GRID 782     // ceil(50000/64)
#define LINK_BLOCKS 3125  // 3125*256 == 800000 == N_EDGES exactly
#define CSTR 136          // LDS C-dump row stride in ushorts

typedef unsigned int uint32;
typedef __attribute__((ext_vector_type(8))) short bf16x8;
typedef __attribute__((ext_vector_type(4))) float f32x4;
typedef __attribute__((ext_vector_type(4))) unsigned int u32x4;   // nt-builtin-safe vec4

__device__ __forceinline__ float bf2f(unsigned int u16) {
    unsigned int x = u16 << 16;
    float f;
    __builtin_memcpy(&f, &x, 4);
    return f;
}
__device__ __forceinline__ unsigned int f2bf(float f) {
    unsigned int x;
    __builtin_memcpy(&x, &f, 4);
    unsigned int r = x + 0x7FFFu + ((x >> 16) & 1u);  // RNE
    return r >> 16;
}
__device__ __forceinline__ uint32 pack_bf2(float a, float b) {
    return f2bf(a) | (f2bf(b) << 16);
}

// ---------------- setup: W^T bf16, Wf^T bf16, head init (64B-padded), sums=0 ----------

__global__ void k_setup(const float* __restrict__ W1, const float* __restrict__ W2,
                        const float* __restrict__ W3, const float* __restrict__ Wf,
                        unsigned short* __restrict__ WT, unsigned short* __restrict__ WfT,
                        int* __restrict__ head, float* __restrict__ sums) {
    int b = blockIdx.x, tid = threadIdx.x;
    if (b < 192) {                       // WT: 3 x 128(n) x 128(k)  (frag = 16B contiguous)
        int idx = b * 256 + tid;
        int mat = idx >> 14, rem = idx & 16383;
        int n = rem >> 7, k = rem & 127;
        const float* W = (mat == 0) ? W1 : ((mat == 1) ? W2 : W3);
        WT[idx] = (unsigned short)f2bf(W[k * 128 + n]);
    } else if (b < 216) {                // WfT: 3 slices x 16(n,pad) x 128(k)
        int idx = (b - 192) * 256 + tid;
        if (idx < 6144) {
            int li = idx >> 11, rem = idx & 2047;
            int n = rem >> 7, k = rem & 127;
            WfT[idx] = (n < C_OUT) ? (unsigned short)f2bf(Wf[(li * 128 + k) * C_OUT + n]) : 0;
        }
    } else {                             // head init + sums zero
        int i = (b - 216) * 256 + tid;
        if (i < N_NODES) head[i << 4] = -1;   // one head per 64B line (atomic de-contention)
        if (i < 768) sums[i] = 0.0f;
    }
}

// ---------------- chain walk: thread-per-node -> padded adj rows + cnt + dinv ----------
// nt stores: adj is write-once streaming; don't leave 12.8MB dirty in L2 (R12
// post-mortem: lazy random-order dirty evictions taxed every later dispatch).

__global__ void k_walk(const int* __restrict__ ei, const int* __restrict__ head,
                       const int* __restrict__ next, int* __restrict__ adj,
                       int* __restrict__ cnt, float* __restrict__ dinv) {
    int i = blockIdx.x * blockDim.x + threadIdx.x;
    if (i >= N_NODES) return;
    int* row = adj + ((size_t)i << 6);
    __builtin_nontemporal_store(i, &row[0]);    // self loop first
    int j = 1;
    int e = head[i << 4];
    while (e >= 0 && j < CAP) {
        __builtin_nontemporal_store(ei[e], &row[j]);
        ++j;
        e = next[e];
    }
    cnt[i] = j;
    dinv[i] = rsqrtf((float)j);                 // deg = chain length + self
}

// ---------------- MFMA GEMM: direct frags, nt streaming loads/stores ------
// hl[M,128](bf16, UNSCALED) = bnrelu(A) @ W. A: Af32 (layer1) XOR Abf (bf16, BN'd).
// A is read-once (nt load); hl written once (nt store -> sequential write-through,
// no dirty-L2 tax). W frags direct from L2-hot WT.
// If linkEi: blocks [0,LINK_BLOCKS) do the adjacency atomicExch build instead.
// mode: 0=none, 1=out = A'@WfT + bias, 2=out += A'@WfT.

__global__ __launch_bounds__(256) void k_gemm(const float* __restrict__ Af32,
                                              const unsigned short* __restrict__ Abf,
                                              const unsigned short* __restrict__ WT,
                                              unsigned short* __restrict__ hl,
                                              const float* __restrict__ sums,
                                              const float* __restrict__ g,
                                              const float* __restrict__ be,
                                              const unsigned short* __restrict__ WfT,
                                              const float* __restrict__ bfv,
                                              float* __restrict__ outp, int mode,
                                              const int* __restrict__ linkEi,
                                              int* __restrict__ head,
                                              int* __restrict__ next) {
    __shared__ unsigned short Cbuf[64 * CSTR];   // 17.4 KB
    __shared__ float scl[128], shl[128];         // 1 KB BN table
    int tid = threadIdx.x;
    int bid = blockIdx.x;

    if (linkEi) {
        if (bid < LINK_BLOCKS) {   // adjacency build: 1 atomic/edge, padded heads
            int e = bid * 256 + tid;              // exactly covers N_EDGES
            int d = linkEi[N_EDGES + e];
            int old = atomicExch(&head[d << 4], e);
            __builtin_nontemporal_store(old, &next[e]);   // sequential stream
            return;
        }
        bid -= LINK_BLOCKS;
    }
    int row0 = bid * 64;

    if (Abf && tid < 128) {
        float mean = sums[tid] * (1.0f / N_NODES);
        float var = fmaxf(sums[128 + tid] * (1.0f / N_NODES) - mean * mean, 0.f);
        float s = g[tid] * rsqrtf(var + BN_EPS);
        scl[tid] = s;
        shl[tid] = be[tid] - mean * s;
    }
    __syncthreads();

    int wave = tid >> 6, lane = tid & 63;
    int quad = lane >> 4, l16 = lane & 15;
    int arow = row0 + wave * 16 + l16;       // this lane's A row
    bool rowok = arow < N_NODES;

    // a-frags direct from global (nt: read-once stream): frag(ks)=A[arow][ks*32+quad*8..+8]
    bf16x8 af[4];
    if (Abf) {
#pragma unroll
        for (int ks = 0; ks < 4; ++ks) {
            int c0 = ks * 32 + quad * 8;
            u32x4 v = (u32x4){0, 0, 0, 0};
            if (rowok) v = __builtin_nontemporal_load((const u32x4*)&Abf[(size_t)arow * 128 + c0]);
            float4 sA = *(float4*)&scl[c0], sB = *(float4*)&scl[c0 + 4];
            float4 tA = *(float4*)&shl[c0], tB = *(float4*)&shl[c0 + 4];
            float sv[8] = {sA.x, sA.y, sA.z, sA.w, sB.x, sB.y, sB.z, sB.w};
            float tv[8] = {tA.x, tA.y, tA.z, tA.w, tB.x, tB.y, tB.z, tB.w};
            uint32 w[4] = {v.x, v.y, v.z, v.w};
            uint32 o[4];
#pragma unroll
            for (int p = 0; p < 4; ++p) {
                float f0 = fmaxf(bf2f(w[p] & 0xFFFFu) * sv[2 * p] + tv[2 * p], 0.f);
                float f1 = fmaxf(bf2f(w[p] >> 16) * sv[2 * p + 1] + tv[2 * p + 1], 0.f);
                o[p] = pack_bf2(f0, f1);
            }
            u32x4 q = (u32x4){o[0], o[1], o[2], o[3]};
            __builtin_memcpy(&af[ks], &q, 16);
        }
    } else {
#pragma unroll
        for (int ks = 0; ks < 4; ++ks) {
            int c0 = ks * 32 + quad * 8;
            f32x4 v0 = (f32x4){0.f, 0.f, 0.f, 0.f};
            f32x4 v1 = (f32x4){0.f, 0.f, 0.f, 0.f};
            if (rowok) {
                v0 = __builtin_nontemporal_load((const f32x4*)&Af32[(size_t)arow * 128 + c0]);
                v1 = __builtin_nontemporal_load((const f32x4*)&Af32[(size_t)arow * 128 + c0 + 4]);
            }
            u32x4 q = (u32x4){pack_bf2(v0.x, v0.y), pack_bf2(v0.z, v0.w),
                              pack_bf2(v1.x, v1.y), pack_bf2(v1.z, v1.w)};
            __builtin_memcpy(&af[ks], &q, 16);
        }
    }

    // MFMA: b-frags direct from global WT (32KB, L2-hot)
    f32x4 acc[8];
#pragma unroll
    for (int nt = 0; nt < 8; ++nt) acc[nt] = (f32x4){0.f, 0.f, 0.f, 0.f};
#pragma unroll
    for (int nt = 0; nt < 8; ++nt) {
        int n = nt * 16 + l16;
#pragma unroll
        for (int ks = 0; ks < 4; ++ks) {
            bf16x8 bw = *(const bf16x8*)&WT[(size_t)n * 128 + ks * 32 + quad * 8];
            acc[nt] = __builtin_amdgcn_mfma_f32_16x16x32_bf16(af[ks], bw, acc[nt], 0, 0, 0);
        }
    }

    // fused readout partial: out (=|+=) bnrelu(A) @ WfT (+bias). 4 extra MFMAs.
    if (mode != 0) {
        f32x4 accO = (f32x4){0.f, 0.f, 0.f, 0.f};
#pragma unroll
        for (int ks = 0; ks < 4; ++ks) {
            bf16x8 bw = *(const bf16x8*)&WfT[l16 * 128 + ks * 32 + quad * 8];
            accO = __builtin_amdgcn_mfma_f32_16x16x32_bf16(af[ks], bw, accO, 0, 0, 0);
        }
        if (l16 < C_OUT) {
#pragma unroll
            for (int reg = 0; reg < 4; ++reg) {
                int m = row0 + wave * 16 + quad * 4 + reg;
                if (m < N_NODES) {
                    size_t o = (size_t)m * C_OUT + l16;
                    float v = accO[reg];
                    if (mode == 1) outp[o] = v + bfv[l16];
                    else outp[o] += v;
                }
            }
        }
    }

    // C-tile: acc -> LDS bf16 -> coalesced nt u32x4 stores (write-through stream)
#pragma unroll
    for (int reg = 0; reg < 4; ++reg) {
        int lm = wave * 16 + quad * 4 + reg;
#pragma unroll
        for (int nt = 0; nt < 8; ++nt)
            Cbuf[lm * CSTR + nt * 16 + l16] = (unsigned short)f2bf(acc[nt][reg]);
    }
    __syncthreads();
    u32x4* H4o = (u32x4*)hl;
#pragma unroll
    for (int i = 0; i < 4; ++i) {
        int idx = i * 256 + tid;
        int r = idx >> 4, c8 = idx & 15;
        int gr = row0 + r;
        if (gr < N_NODES)
            __builtin_nontemporal_store(*(u32x4*)&Cbuf[r * CSTR + c8 * 8],
                                        &H4o[(size_t)gr * 16 + c8]);
    }
}

// ---------------- Aggregation: wave/node, unroll-8 MLP, per-edge dinv, nt bf16 out -----

__global__ void k_agg(const unsigned short* __restrict__ hl, const int* __restrict__ adj,
                      const int* __restrict__ cnt, const float* __restrict__ dinv,
                      unsigned short* __restrict__ agg) {
    int node = (int)((blockIdx.x * blockDim.x + threadIdx.x) >> 6);
    int lane = threadIdx.x & 63;
    if (node >= N_NODES) return;
    const int* row = adj + ((size_t)node << 6);   // wave-uniform scalar reads
    int n = cnt[node];
    float ax = 0.f, ay = 0.f;
    int e = 0;
    for (; e + 7 < n; e += 8) {
        int j[8];
#pragma unroll
        for (int u = 0; u < 8; ++u) j[u] = row[e + u];
        float w[8];
        uint32 p[8];
#pragma unroll
        for (int u = 0; u < 8; ++u) {
            w[u] = dinv[j[u]];
            p[u] = *(const uint32*)&hl[(size_t)j[u] * 128 + lane * 2];
        }
#pragma unroll
        for (int u = 0; u < 8; ++u) {
            ax += bf2f(p[u] & 0xFFFFu) * w[u];
            ay += bf2f(p[u] >> 16) * w[u];
        }
    }
    for (; e < n; ++e) {
        int j = row[e];
        float w = dinv[j];
        uint32 p = *(const uint32*)&hl[(size_t)j * 128 + lane * 2];
        ax += bf2f(p & 0xFFFFu) * w;
        ay += bf2f(p >> 16) * w;
    }
    float di = dinv[node];
    uint32 outv = pack_bf2(ax * di, ay * di);
    __builtin_nontemporal_store(outv, (uint32*)&agg[(size_t)node * 128 + lane * 2]);
}

// ---------------- BN stats over bf16 agg (uint32/lane, 4-wave LDS reduce) ----------------

__global__ __launch_bounds__(256) void k_bn_stats(const unsigned short* __restrict__ agg,
                                                  float* __restrict__ sums) {
    __shared__ float red[4][256];
    int tid = threadIdx.x;
    int lane = tid & 63, w = tid >> 6;
    float sx = 0.f, qx = 0.f, sy = 0.f, qy = 0.f;
    for (int r = blockIdx.x * 4 + w; r < N_NODES; r += gridDim.x * 4) {
        uint32 p = __builtin_nontemporal_load((const uint32*)&agg[(size_t)r * 128 + lane * 2]);
        float x = bf2f(p & 0xFFFFu), y = bf2f(p >> 16);
        sx += x; qx += x * x; sy += y; qy += y * y;
    }
    red[0][tid] = sx; red[1][tid] = qx; red[2][tid] = sy; red[3][tid] = qy;
    __syncthreads();
    int s = tid >> 6, l = tid & 63;
    float v = red[s][l] + red[s][64 + l] + red[s][128 + l] + red[s][192 + l];
    atomicAdd(&sums[(s & 1) * 128 + 2 * l + (s >> 1)], v);
}

// ---------------- Layer-3 readout: MFMA, out += bnrelu(h3) @ WfT-slice2 ----------------

__global__ __launch_bounds__(256) void k_out_mfma(const unsigned short* __restrict__ h,
                                                  const unsigned short* __restrict__ WfT,
                                                  float* __restrict__ outp,
                                                  const float* __restrict__ sums,
                                                  const float* __restrict__ g,
                                                  const float* __restrict__ be) {
    __shared__ float scl[128], shl[128];
    int tid = threadIdx.x;
    int row0 = blockIdx.x * 64;

    if (tid < 128) {
        float mean = sums[tid] * (1.0f / N_NODES);
        float var = fmaxf(sums[128 + tid] * (1.0f / N_NODES) - mean * mean, 0.f);
        float s = g[tid] * rsqrtf(var + BN_EPS);
        scl[tid] = s;
        shl[tid] = be[tid] - mean * s;
    }
    __syncthreads();

    int wave = tid >> 6, lane = tid & 63;
    int quad = lane >> 4, l16 = lane & 15;
    int arow = row0 + wave * 16 + l16;
    bool rowok = arow < N_NODES;

    f32x4 accO = (f32x4){0.f, 0.f, 0.f, 0.f};
#pragma unroll
    for (int ks = 0; ks < 4; ++ks) {
        int c0 = ks * 32 + quad * 8;
        u32x4 v = (u32x4){0, 0, 0, 0};
        if (rowok) v = __builtin_nontemporal_load((const u32x4*)&h[(size_t)arow * 128 + c0]);
        float4 sA = *(float4*)&scl[c0], sB = *(float4*)&scl[c0 + 4];
        float4 tA = *(float4*)&shl[c0], tB = *(float4*)&shl[c0 + 4];
        float sv[8] = {sA.x, sA.y, sA.z, sA.w, sB.x, sB.y, sB.z, sB.w};
        float tv[8] = {tA.x, tA.y, tA.z, tA.w, tB.x, tB.y, tB.z, tB.w};
        uint32 w[4] = {v.x, v.y, v.z, v.w};
        uint32 o[4];
#pragma unroll
        for (int p = 0; p < 4; ++p) {
            float f0 = fmaxf(bf2f(w[p] & 0xFFFFu) * sv[2 * p] + tv[2 * p], 0.f);
            float f1 = fmaxf(bf2f(w[p] >> 16) * sv[2 * p + 1] + tv[2 * p + 1], 0.f);
            o[p] = pack_bf2(f0, f1);
        }
        u32x4 q = (u32x4){o[0], o[1], o[2], o[3]};
        bf16x8 av;
        __builtin_memcpy(&av, &q, 16);
        bf16x8 bw = *(const bf16x8*)&WfT[l16 * 128 + c0];
        accO = __builtin_amdgcn_mfma_f32_16x16x32_bf16(av, bw, accO, 0, 0, 0);
    }
    if (l16 < C_OUT) {
#pragma unroll
        for (int reg = 0; reg < 4; ++reg) {
            int m = row0 + wave * 16 + quad * 4 + reg;
            if (m < N_NODES)
                outp[(size_t)m * C_OUT + l16] += accO[reg];
        }
    }
}

// ---------------- launch ----------------

extern "C" void kernel_launch(void* const* d_in, const int* in_sizes, int n_in,
                              void* d_out, int out_size, void* d_ws, size_t ws_size,
                              hipStream_t stream) {
    const float* x  = (const float*)d_in[0];
    const int*   ei = (const int*)d_in[1];
    const float* W1 = (const float*)d_in[2];
    const float* W2 = (const float*)d_in[4];
    const float* W3 = (const float*)d_in[6];
    // b1/b2/b3 absorbed exactly by BN mean-subtraction
    const float* g1  = (const float*)d_in[8];
    const float* be1 = (const float*)d_in[9];
    const float* g2  = (const float*)d_in[10];
    const float* be2 = (const float*)d_in[11];
    const float* g3  = (const float*)d_in[12];
    const float* be3 = (const float*)d_in[13];
    const float* Wf  = (const float*)d_in[14];
    const float* bf  = (const float*)d_in[15];
    float* out = (float*)d_out;

    char* ws = (char*)d_ws;
    size_t off = 0;
    auto alloc = [&](size_t bytes) -> void* {
        void* p = ws + off;
        off = (off + bytes + 255) & ~(size_t)255;
        return p;
    };
    int*   head  = (int*)alloc((size_t)N_NODES * 16 * 4);    // 64B-padded heads, 3.2MB
    int*   next  = (int*)alloc((size_t)N_EDGES * 4);
    int*   adj   = (int*)alloc((size_t)N_NODES * CAP * 4);   // 12.8 MB padded rows
    int*   cnt   = (int*)alloc((size_t)N_NODES * 4);
    float* dinv  = (float*)alloc((size_t)N_NODES * 4);
    float* sums  = (float*)alloc(768 * 4);
    unsigned short* WT   = (unsigned short*)alloc((size_t)3 * 128 * 128 * 2);
    unsigned short* WfT  = (unsigned short*)alloc((size_t)3 * 16 * 128 * 2);
    unsigned short* hl   = (unsigned short*)alloc((size_t)N_NODES * 128 * 2);  // bf16
    unsigned short* bufA = (unsigned short*)alloc((size_t)N_NODES * 128 * 2);  // bf16 agg
    unsigned short* bufB = (unsigned short*)alloc((size_t)N_NODES * 128 * 2);  // bf16 agg

    const int TPB = 256;
    k_setup<<<412, 256, 0, stream>>>(W1, W2, W3, Wf, WT, WfT, head, sums);

    const int agg_grid = (N_NODES + 3) / 4;            // wave per node, 4/block

    // ---- layer 1 GEMM fused with adjacency link build (independent work) ----
    k_gemm<<<LINK_BLOCKS + GEMM_GRID, 256, 0, stream>>>(
        x, nullptr, WT, hl, nullptr, nullptr, nullptr,
        nullptr, nullptr, nullptr, 0, ei, head, next);
    k_walk<<<(N_NODES + TPB - 1) / TPB, TPB, 0, stream>>>(ei, head, next, adj, cnt, dinv);
    k_agg<<<agg_grid, 256, 0, stream>>>(hl, adj, cnt, dinv, bufA);
    k_bn_stats<<<512, 256, 0, stream>>>(bufA, sums + 0);

    // ---- layer 2 (gemm also emits out = h1 @ Wf0 + bf) ----
    k_gemm<<<GEMM_GRID, 256, 0, stream>>>(nullptr, bufA, WT + 16384, hl, sums + 0, g1, be1,
                                          WfT, bf, out, 1, nullptr, nullptr, nullptr);
    k_agg<<<agg_grid, 256, 0, stream>>>(hl, adj, cnt, dinv, bufB);
    k_bn_stats<<<512, 256, 0, stream>>>(bufB, sums + 256);

    // ---- layer 3 (gemm also emits out += h2 @ Wf1) ----
    k_gemm<<<GEMM_GRID, 256, 0, stream>>>(nullptr, bufB, WT + 32768, hl, sums + 256, g2, be2,
                                          WfT + 2048, nullptr, out, 2, nullptr, nullptr, nullptr);
    k_agg<<<agg_grid, 256, 0, stream>>>(hl, adj, cnt, dinv, bufA);
    k_bn_stats<<<512, 256, 0, stream>>>(bufA, sums + 512);

    // ---- layer 3 readout (MFMA, direct frags) ----
    k_out_mfma<<<GEMM_GRID, 256, 0, stream>>>(bufA, WfT + 4096, out, sums + 512, g3, be3);
}

// Round 15
// 415.093 us; speedup vs baseline: 1.1253x; 1.1253x over previous
//
#include <hip/hip_runtime.h>

#define N_NODES 50000
#define N_EDGES 800000
#define D 128
#define C_OUT 10
#define BN_EPS 1e-5f
#define CAP 64            // padded adjacency row capacity; P(deg>=63)~1e-17 (Poisson 16)
#define GEMM_GRID 391     // ceil(50000/128)
#define LINK_BLOCKS 3125  // 3125*256 == 800000 == N_EDGES exactly
#define CSTR 136          // LDS C-dump row stride in ushorts
#define AGG_GRID 12544    // 8 xcd-lanes x 49 tile-slots x 32 groups (covers 12500)

typedef unsigned int uint32;
typedef __attribute__((ext_vector_type(8))) short bf16x8;
typedef __attribute__((ext_vector_type(4))) float f32x4;

__device__ __forceinline__ float bf2f(unsigned int u16) {
    unsigned int x = u16 << 16;
    float f;
    __builtin_memcpy(&f, &x, 4);
    return f;
}
__device__ __forceinline__ unsigned int f2bf(float f) {
    unsigned int x;
    __builtin_memcpy(&x, &f, 4);
    unsigned int r = x + 0x7FFFu + ((x >> 16) & 1u);  // RNE
    return r >> 16;
}
__device__ __forceinline__ uint32 pack_bf2(float a, float b) {
    return f2bf(a) | (f2bf(b) << 16);
}

// ---------------- setup: W^T bf16, Wf^T bf16, head init (64B-padded), sums=0 ----------

__global__ void k_setup(const float* __restrict__ W1, const float* __restrict__ W2,
                        const float* __restrict__ W3, const float* __restrict__ Wf,
                        unsigned short* __restrict__ WT, unsigned short* __restrict__ WfT,
                        int* __restrict__ head, float* __restrict__ sums) {
    int b = blockIdx.x, tid = threadIdx.x;
    if (b < 192) {                       // WT: 3 x 128(n) x 128(k)
        int idx = b * 256 + tid;
        int mat = idx >> 14, rem = idx & 16383;
        int n = rem >> 7, k = rem & 127;
        const float* W = (mat == 0) ? W1 : ((mat == 1) ? W2 : W3);
        WT[idx] = (unsigned short)f2bf(W[k * 128 + n]);
    } else if (b < 216) {                // WfT: 3 slices x 16(n,pad) x 128(k)
        int idx = (b - 192) * 256 + tid;
        if (idx < 6144) {
            int li = idx >> 11, rem = idx & 2047;
            int n = rem >> 7, k = rem & 127;
            WfT[idx] = (n < C_OUT) ? (unsigned short)f2bf(Wf[(li * 128 + k) * C_OUT + n]) : 0;
        }
    } else {                             // head init + sums zero
        int i = (b - 216) * 256 + tid;
        if (i < N_NODES) head[i << 4] = -1;   // one head per 64B line (atomic de-contention)
        if (i < 768) sums[i] = 0.0f;
    }
}

// ---------------- chain walk: thread-per-node -> padded adj rows + cnt + dinv ----------

__global__ void k_walk(const int* __restrict__ ei, const int* __restrict__ head,
                       const int* __restrict__ next, int* __restrict__ adj,
                       int* __restrict__ cnt, float* __restrict__ dinv) {
    int i = blockIdx.x * blockDim.x + threadIdx.x;
    if (i >= N_NODES) return;
    int* row = adj + ((size_t)i << 6);
    row[0] = i;                                 // self loop first
    int j = 1;
    int e = head[i << 4];
    while (e >= 0 && j < CAP) {
        row[j++] = ei[e];                       // source id
        e = next[e];
    }
    cnt[i] = j;
    dinv[i] = rsqrtf((float)j);                 // deg = chain length + self
}

// ---------------- MFMA GEMM (R11-best: 128-tile LDS-staged, LDS C-dump) ------
// hl[M,128](bf16, UNSCALED) = bnrelu(A) @ W. A: Af32 (layer1) XOR Abf (bf16, BN'd).
// If linkEi: blocks [0,LINK_BLOCKS) do the adjacency atomicExch build instead.
// mode: 0=none, 1=out = staged@WfT + bias, 2=out += staged@WfT.

__global__ __launch_bounds__(256) void k_gemm(const float* __restrict__ Af32,
                                              const unsigned short* __restrict__ Abf,
                                              const unsigned short* __restrict__ WT,
                                              unsigned short* __restrict__ hl,
                                              const float* __restrict__ sums,
                                              const float* __restrict__ g,
                                              const float* __restrict__ be,
                                              const unsigned short* __restrict__ WfT,
                                              const float* __restrict__ bfv,
                                              float* __restrict__ outp, int mode,
                                              const int* __restrict__ linkEi,
                                              int* __restrict__ head,
                                              int* __restrict__ next) {
    __shared__ unsigned short SM[32768];      // 64 KB: As=SM[0:16384), Ws=SM[16384:32768)
    unsigned short* As = SM;
    unsigned short* Ws = SM + 16384;
    int tid = threadIdx.x;
    int bid = blockIdx.x;

    if (linkEi) {
        if (bid < LINK_BLOCKS) {   // adjacency build: 1 atomic/edge, padded heads
            int e = bid * 256 + tid;              // exactly covers N_EDGES
            int d = linkEi[N_EDGES + e];
            next[e] = atomicExch(&head[d << 4], e);
            return;
        }
        bid -= LINK_BLOCKS;
    }
    int row0 = bid * 128;

    // stage Ws (bf16 W^T [n][k]); XOR swizzle in 16B blocks: 2-way conflicts max (free)
    const ushort4* WT4 = (const ushort4*)WT;
#pragma unroll
    for (int i = 0; i < 16; ++i) {
        int idx = i * 256 + tid;
        int r = idx >> 5, c4 = idx & 31;
        ushort4 v = WT4[idx];
        int swz = (c4 >> 1) ^ (r & 15);
        *(ushort4*)&Ws[r * 128 + swz * 8 + (c4 & 1) * 4] = v;
    }

    if (Abf) {
        // bf16 A path: thread stages 8 fixed columns cc..cc+7 (c8 = tid&15)
        int c8 = tid & 15, cc = c8 * 8;
        float s8[8], t8[8];
#pragma unroll
        for (int u = 0; u < 8; ++u) {
            float mean = sums[cc + u] * (1.0f / N_NODES);
            float var = fmaxf(sums[128 + cc + u] * (1.0f / N_NODES) - mean * mean, 0.f);
            float s = g[cc + u] * rsqrtf(var + BN_EPS);
            s8[u] = s;
            t8[u] = be[cc + u] - mean * s;
        }
        const uint4* H4 = (const uint4*)Abf;
#pragma unroll
        for (int i = 0; i < 8; ++i) {
            int idx = i * 256 + tid;
            int r = idx >> 4;                   // 0..127
            int gr = row0 + r;
            uint4 v = make_uint4(0, 0, 0, 0);
            if (gr < N_NODES) v = H4[(size_t)gr * 16 + c8];
            uint32 w[4] = {v.x, v.y, v.z, v.w};
            uint32 o[4];
#pragma unroll
            for (int p = 0; p < 4; ++p) {
                float f0 = bf2f(w[p] & 0xFFFFu) * s8[2 * p] + t8[2 * p];
                float f1 = bf2f(w[p] >> 16) * s8[2 * p + 1] + t8[2 * p + 1];
                o[p] = pack_bf2(fmaxf(f0, 0.f), fmaxf(f1, 0.f));
            }
            int swz = c8 ^ (r & 15);
            *(uint4*)&As[r * 128 + swz * 8] = make_uint4(o[0], o[1], o[2], o[3]);
        }
    } else {
        // fp32 A path (layer 1: x, no BN)
        const float4* A4 = (const float4*)Af32;
#pragma unroll
        for (int i = 0; i < 16; ++i) {
            int idx = i * 256 + tid;
            int r = idx >> 5, c4 = idx & 31;
            int gr = row0 + r;
            float4 v = make_float4(0.f, 0.f, 0.f, 0.f);
            if (gr < N_NODES) v = A4[(size_t)gr * 32 + c4];
            ushort4 o;
            o.x = (unsigned short)f2bf(v.x);
            o.y = (unsigned short)f2bf(v.y);
            o.z = (unsigned short)f2bf(v.z);
            o.w = (unsigned short)f2bf(v.w);
            int swz = (c4 >> 1) ^ (r & 15);
            *(ushort4*)&As[r * 128 + swz * 8 + (c4 & 1) * 4] = o;
        }
    }
    __syncthreads();

    int wave = tid >> 6, lane = tid & 63;
    int quad = lane >> 4, l16 = lane & 15;
    int m0 = wave * 32;

    // a-frags: A[m=lane&15][k = ks*32 + quad*8 + j]
    bf16x8 af[2][4];
#pragma unroll
    for (int mt = 0; mt < 2; ++mt) {
        int m = m0 + mt * 16 + l16;
#pragma unroll
        for (int ks = 0; ks < 4; ++ks) {
            int swz = (ks * 4 + quad) ^ (m & 15);
            af[mt][ks] = *(bf16x8*)&As[m * 128 + swz * 8];
        }
    }

    f32x4 acc[8][2];
#pragma unroll
    for (int nt = 0; nt < 8; ++nt)
#pragma unroll
        for (int mt = 0; mt < 2; ++mt) acc[nt][mt] = (f32x4){0.f, 0.f, 0.f, 0.f};

#pragma unroll
    for (int nt = 0; nt < 8; ++nt) {
        int n = nt * 16 + l16;
        bf16x8 bfr[4];
#pragma unroll
        for (int ks = 0; ks < 4; ++ks) {
            int swz = (ks * 4 + quad) ^ (n & 15);
            bfr[ks] = *(bf16x8*)&Ws[n * 128 + swz * 8];
        }
#pragma unroll
        for (int mt = 0; mt < 2; ++mt)
#pragma unroll
            for (int ks = 0; ks < 4; ++ks)
                acc[nt][mt] = __builtin_amdgcn_mfma_f32_16x16x32_bf16(
                    af[mt][ks], bfr[ks], acc[nt][mt], 0, 0, 0);
    }

    // fused readout partial: out (=|+=) staged @ WfT (+bias). 8 extra MFMAs.
    if (mode != 0) {
        f32x4 accO[2] = {(f32x4){0.f, 0.f, 0.f, 0.f}, (f32x4){0.f, 0.f, 0.f, 0.f}};
#pragma unroll
        for (int ks = 0; ks < 4; ++ks) {
            int chunk = ks * 4 + quad;
            bf16x8 bw = *(const bf16x8*)&WfT[l16 * 128 + chunk * 8];  // tiny, L2-hot
            accO[0] = __builtin_amdgcn_mfma_f32_16x16x32_bf16(af[0][ks], bw, accO[0], 0, 0, 0);
            accO[1] = __builtin_amdgcn_mfma_f32_16x16x32_bf16(af[1][ks], bw, accO[1], 0, 0, 0);
        }
        if (l16 < C_OUT) {
#pragma unroll
            for (int mt = 0; mt < 2; ++mt)
#pragma unroll
                for (int reg = 0; reg < 4; ++reg) {
                    int m = row0 + m0 + mt * 16 + quad * 4 + reg;
                    if (m < N_NODES) {
                        size_t o = (size_t)m * C_OUT + l16;
                        float v = accO[mt][reg];
                        if (mode == 1) outp[o] = v + bfv[l16];
                        else outp[o] += v;
                    }
                }
        }
    }

    // C-tile: acc -> LDS bf16 -> coalesced uint4 stores
    __syncthreads();   // all waves done reading As/Ws
#pragma unroll
    for (int mt = 0; mt < 2; ++mt) {
#pragma unroll
        for (int reg = 0; reg < 4; ++reg) {
            int lm = m0 + mt * 16 + quad * 4 + reg;    // local row 0..127
#pragma unroll
            for (int nt = 0; nt < 8; ++nt)
                SM[lm * CSTR + nt * 16 + l16] = (unsigned short)f2bf(acc[nt][mt][reg]);
        }
    }
    __syncthreads();
    uint4* H4o = (uint4*)hl;
#pragma unroll
    for (int i = 0; i < 8; ++i) {
        int idx = i * 256 + tid;
        int r = idx >> 4, c8 = idx & 15;
        int gr = row0 + r;
        if (gr < N_NODES)
            H4o[(size_t)gr * 16 + c8] = *(uint4*)&SM[r * CSTR + c8 * 8];
    }
}

// ---------------- Aggregation: wave/node, unroll-8, per-edge dinv, XCD-swizzled --------
// Swizzle: all 32 node-groups that feed gemm tile g are handled by blocks with
// blockIdx % 8 == g % 8, so (if block->XCD is round-robin %8) the NEXT gemm's
// A-read of bufA rows [128g,128g+128) hits the SAME XCD's L2 that dirtied them.

__global__ void k_agg(const unsigned short* __restrict__ hl, const int* __restrict__ adj,
                      const int* __restrict__ cnt, const float* __restrict__ dinv,
                      unsigned short* __restrict__ agg) {
    int b = blockIdx.x;
    int x = b & 7, q = b >> 3;
    int gt = x + ((q >> 5) << 3);           // gemm tile this block serves; gt%8 == x
    int ng = (gt << 5) + (q & 31);          // node-group (4 nodes)
    if (ng >= 12500) return;
    int node = (ng << 2) + (threadIdx.x >> 6);
    int lane = threadIdx.x & 63;
    if (node >= N_NODES) return;
    const int* row = adj + ((size_t)node << 6);   // wave-uniform scalar reads
    int n = cnt[node];
    float ax = 0.f, ay = 0.f;
    int e = 0;
    for (; e + 7 < n; e += 8) {
        int j[8];
#pragma unroll
        for (int u = 0; u < 8; ++u) j[u] = row[e + u];
        float w[8];
        uint32 p[8];
#pragma unroll
        for (int u = 0; u < 8; ++u) {
            w[u] = dinv[j[u]];
            p[u] = *(const uint32*)&hl[(size_t)j[u] * 128 + lane * 2];
        }
#pragma unroll
        for (int u = 0; u < 8; ++u) {
            ax += bf2f(p[u] & 0xFFFFu) * w[u];
            ay += bf2f(p[u] >> 16) * w[u];
        }
    }
    for (; e < n; ++e) {
        int j = row[e];
        float w = dinv[j];
        uint32 p = *(const uint32*)&hl[(size_t)j * 128 + lane * 2];
        ax += bf2f(p & 0xFFFFu) * w;
        ay += bf2f(p >> 16) * w;
    }
    float di = dinv[node];
    *(uint32*)&agg[(size_t)node * 128 + lane * 2] = pack_bf2(ax * di, ay * di);
}

// ---------------- BN stats over bf16 agg (uint32/lane, 4-wave LDS reduce) ----------------

__global__ __launch_bounds__(256) void k_bn_stats(const unsigned short* __restrict__ agg,
                                                  float* __restrict__ sums) {
    __shared__ float red[4][256];
    int tid = threadIdx.x;
    int lane = tid & 63, w = tid >> 6;
    float sx = 0.f, qx = 0.f, sy = 0.f, qy = 0.f;
    for (int r = blockIdx.x * 4 + w; r < N_NODES; r += gridDim.x * 4) {
        uint32 p = *(const uint32*)&agg[(size_t)r * 128 + lane * 2];
        float x = bf2f(p & 0xFFFFu), y = bf2f(p >> 16);
        sx += x; qx += x * x; sy += y; qy += y * y;
    }
    red[0][tid] = sx; red[1][tid] = qx; red[2][tid] = sy; red[3][tid] = qy;
    __syncthreads();
    int s = tid >> 6, l = tid & 63;
    float v = red[s][l] + red[s][64 + l] + red[s][128 + l] + red[s][192 + l];
    atomicAdd(&sums[(s & 1) * 128 + 2 * l + (s >> 1)], v);
}

// ---------------- Layer-3 readout: MFMA, out += bnrelu(h3) @ WfT-slice2 ----------------

__global__ __launch_bounds__(256) void k_out_mfma(const unsigned short* __restrict__ h,
                                                  const unsigned short* __restrict__ WfT,
                                                  float* __restrict__ outp,
                                                  const float* __restrict__ sums,
                                                  const float* __restrict__ g,
                                                  const float* __restrict__ be) {
    __shared__ unsigned short As[128 * 128];  // 32 KB
    int tid = threadIdx.x;
    int row0 = blockIdx.x * 128;

    int c8 = tid & 15, cc = c8 * 8;
    float s8[8], t8[8];
#pragma unroll
    for (int u = 0; u < 8; ++u) {
        float mean = sums[cc + u] * (1.0f / N_NODES);
        float var = fmaxf(sums[128 + cc + u] * (1.0f / N_NODES) - mean * mean, 0.f);
        float s = g[cc + u] * rsqrtf(var + BN_EPS);
        s8[u] = s;
        t8[u] = be[cc + u] - mean * s;
    }
    const uint4* H4 = (const uint4*)h;
#pragma unroll
    for (int i = 0; i < 8; ++i) {
        int idx = i * 256 + tid;
        int r = idx >> 4;
        int gr = row0 + r;
        uint4 v = make_uint4(0, 0, 0, 0);
        if (gr < N_NODES) v = H4[(size_t)gr * 16 + c8];
        uint32 w[4] = {v.x, v.y, v.z, v.w};
        uint32 o[4];
#pragma unroll
        for (int p = 0; p < 4; ++p) {
            float f0 = bf2f(w[p] & 0xFFFFu) * s8[2 * p] + t8[2 * p];
            float f1 = bf2f(w[p] >> 16) * s8[2 * p + 1] + t8[2 * p + 1];
            o[p] = pack_bf2(fmaxf(f0, 0.f), fmaxf(f1, 0.f));
        }
        int swz = c8 ^ (r & 15);
        *(uint4*)&As[r * 128 + swz * 8] = make_uint4(o[0], o[1], o[2], o[3]);
    }
    __syncthreads();

    int wave = tid >> 6, lane = tid & 63;
    int quad = lane >> 4, l16 = lane & 15;
    int m0 = wave * 32;

    f32x4 accO[2] = {(f32x4){0.f, 0.f, 0.f, 0.f}, (f32x4){0.f, 0.f, 0.f, 0.f}};
#pragma unroll
    for (int ks = 0; ks < 4; ++ks) {
        bf16x8 bw = *(const bf16x8*)&WfT[l16 * 128 + (ks * 4 + quad) * 8];
#pragma unroll
        for (int mt = 0; mt < 2; ++mt) {
            int m = m0 + mt * 16 + l16;
            int swz = (ks * 4 + quad) ^ (m & 15);
            bf16x8 av = *(bf16x8*)&As[m * 128 + swz * 8];
            accO[mt] = __builtin_amdgcn_mfma_f32_16x16x32_bf16(av, bw, accO[mt], 0, 0, 0);
        }
    }
    if (l16 < C_OUT) {
#pragma unroll
        for (int mt = 0; mt < 2; ++mt)
#pragma unroll
            for (int reg = 0; reg < 4; ++reg) {
                int m = row0 + m0 + mt * 16 + quad * 4 + reg;
                if (m < N_NODES)
                    outp[(size_t)m * C_OUT + l16] += accO[mt][reg];
            }
    }
}

// ---------------- launch ----------------

extern "C" void kernel_launch(void* const* d_in, const int* in_sizes, int n_in,
                              void* d_out, int out_size, void* d_ws, size_t ws_size,
                              hipStream_t stream) {
    const float* x  = (const float*)d_in[0];
    const int*   ei = (const int*)d_in[1];
    const float* W1 = (const float*)d_in[2];
    const float* W2 = (const float*)d_in[4];
    const float* W3 = (const float*)d_in[6];
    // b1/b2/b3 absorbed exactly by BN mean-subtraction
    const float* g1  = (const float*)d_in[8];
    const float* be1 = (const float*)d_in[9];
    const float* g2  = (const float*)d_in[10];
    const float* be2 = (const float*)d_in[11];
    const float* g3  = (const float*)d_in[12];
    const float* be3 = (const float*)d_in[13];
    const float* Wf  = (const float*)d_in[14];
    const float* bf  = (const float*)d_in[15];
    float* out = (float*)d_out;

    char* ws = (char*)d_ws;
    size_t off = 0;
    auto alloc = [&](size_t bytes) -> void* {
        void* p = ws + off;
        off = (off + bytes + 255) & ~(size_t)255;
        return p;
    };
    int*   head  = (int*)alloc((size_t)N_NODES * 16 * 4);    // 64B-padded heads, 3.2MB
    int*   next  = (int*)alloc((size_t)N_EDGES * 4);
    int*   adj   = (int*)alloc((size_t)N_NODES * CAP * 4);   // 12.8 MB padded rows
    int*   cnt   = (int*)alloc((size_t)N_NODES * 4);
    float* dinv  = (float*)alloc((size_t)N_NODES * 4);
    float* sums  = (float*)alloc(768 * 4);
    unsigned short* WT   = (unsigned short*)alloc((size_t)3 * 128 * 128 * 2);
    unsigned short* WfT  = (unsigned short*)alloc((size_t)3 * 16 * 128 * 2);
    unsigned short* hl   = (unsigned short*)alloc((size_t)N_NODES * 128 * 2);  // bf16
    unsigned short* bufA = (unsigned short*)alloc((size_t)N_NODES * 128 * 2);  // bf16 agg
    unsigned short* bufB = (unsigned short*)alloc((size_t)N_NODES * 128 * 2);  // bf16 agg

    const int TPB = 256;
    k_setup<<<412, 256, 0, stream>>>(W1, W2, W3, Wf, WT, WfT, head, sums);

    // ---- layer 1 GEMM fused with adjacency link build (independent work) ----
    k_gemm<<<LINK_BLOCKS + GEMM_GRID, 256, 0, stream>>>(
        x, nullptr, WT, hl, nullptr, nullptr, nullptr,
        nullptr, nullptr, nullptr, 0, ei, head, next);
    k_walk<<<(N_NODES + TPB - 1) / TPB, TPB, 0, stream>>>(ei, head, next, adj, cnt, dinv);
    k_agg<<<AGG_GRID, 256, 0, stream>>>(hl, adj, cnt, dinv, bufA);
    k_bn_stats<<<512, 256, 0, stream>>>(bufA, sums + 0);

    // ---- layer 2 (gemm also emits out = h1 @ Wf0 + bf) ----
    k_gemm<<<GEMM_GRID, 256, 0, stream>>>(nullptr, bufA, WT + 16384, hl, sums + 0, g1, be1,
                                          WfT, bf, out, 1, nullptr, nullptr, nullptr);
    k_agg<<<AGG_GRID, 256, 0, stream>>>(hl, adj, cnt, dinv, bufB);
    k_bn_stats<<<512, 256, 0, stream>>>(bufB, sums + 256);

    // ---- layer 3 (gemm also emits out += h2 @ Wf1) ----
    k_gemm<<<GEMM_GRID, 256, 0, stream>>>(nullptr, bufB, WT + 32768, hl, sums + 256, g2, be2,
                                          WfT + 2048, nullptr, out, 2, nullptr, nullptr, nullptr);
    k_agg<<<AGG_GRID, 256, 0, stream>>>(hl, adj, cnt, dinv, bufA);
    k_bn_stats<<<512, 256, 0, stream>>>(bufA, sums + 512);

    // ---- layer 3 readout (MFMA) ----
    k_out_mfma<<<GEMM_GRID, 256, 0, stream>>>(bufA, WfT + 4096, out, sums + 512, g3, be3);
}

// Round 16
// 413.973 us; speedup vs baseline: 1.1284x; 1.0027x over previous
//
#include <hip/hip_runtime.h>

#define N_NODES 50000
#define N_EDGES 800000
#define D 128
#define C_OUT 10
#define BN_EPS 1e-5f
#define CAP 64            // padded adjacency row capacity; P(deg>=63)~1e-17 (Poisson 16)
#define GEMM_GRID 391     // ceil(50000/128)
#define LINK_BLOCKS 3125  // 3125*256 == 800000 == N_EDGES exactly
#define CSTR 136          // LDS C-dump row stride in ushorts

typedef unsigned int uint32;
typedef __attribute__((ext_vector_type(8))) short bf16x8;
typedef __attribute__((ext_vector_type(4))) float f32x4;

__device__ __forceinline__ float bf2f(unsigned int u16) {
    unsigned int x = u16 << 16;
    float f;
    __builtin_memcpy(&f, &x, 4);
    return f;
}
__device__ __forceinline__ unsigned int f2bf(float f) {
    unsigned int x;
    __builtin_memcpy(&x, &f, 4);
    unsigned int r = x + 0x7FFFu + ((x >> 16) & 1u);  // RNE
    return r >> 16;
}
__device__ __forceinline__ uint32 pack_bf2(float a, float b) {
    return f2bf(a) | (f2bf(b) << 16);
}

// ---------------- setup: W^T bf16, Wf^T bf16, head init (64B-padded), sums=0 ----------

__global__ void k_setup(const float* __restrict__ W1, const float* __restrict__ W2,
                        const float* __restrict__ W3, const float* __restrict__ Wf,
                        unsigned short* __restrict__ WT, unsigned short* __restrict__ WfT,
                        int* __restrict__ head, float* __restrict__ sums) {
    int b = blockIdx.x, tid = threadIdx.x;
    if (b < 192) {                       // WT: 3 x 128(n) x 128(k)
        int idx = b * 256 + tid;
        int mat = idx >> 14, rem = idx & 16383;
        int n = rem >> 7, k = rem & 127;
        const float* W = (mat == 0) ? W1 : ((mat == 1) ? W2 : W3);
        WT[idx] = (unsigned short)f2bf(W[k * 128 + n]);
    } else if (b < 216) {                // WfT: 3 slices x 16(n,pad) x 128(k)
        int idx = (b - 192) * 256 + tid;
        if (idx < 6144) {
            int li = idx >> 11, rem = idx & 2047;
            int n = rem >> 7, k = rem & 127;
            WfT[idx] = (n < C_OUT) ? (unsigned short)f2bf(Wf[(li * 128 + k) * C_OUT + n]) : 0;
        }
    } else {                             // head init + sums zero
        int i = (b - 216) * 256 + tid;
        if (i < N_NODES) head[i << 4] = -1;   // one head per 64B line (atomic de-contention)
        if (i < 768) sums[i] = 0.0f;
    }
}

// ---------------- chain walk: thread-per-node -> padded adj rows + cnt + dinv ----------

__global__ void k_walk(const int* __restrict__ ei, const int* __restrict__ head,
                       const int* __restrict__ next, int* __restrict__ adj,
                       int* __restrict__ cnt, float* __restrict__ dinv) {
    int i = blockIdx.x * blockDim.x + threadIdx.x;
    if (i >= N_NODES) return;
    int* row = adj + ((size_t)i << 6);
    row[0] = i;                                 // self loop first
    int j = 1;
    int e = head[i << 4];
    while (e >= 0 && j < CAP) {
        row[j++] = ei[e];                       // source id
        e = next[e];
    }
    cnt[i] = j;
    dinv[i] = rsqrtf((float)j);                 // deg = chain length + self
}

// ---------------- MFMA GEMM (R11-best: 128-tile LDS-staged, LDS C-dump) ------
// hl[M,128](bf16, UNSCALED) = bnrelu(A) @ W. A: Af32 (layer1) XOR Abf (bf16, BN'd).
// If linkEi: blocks [0,LINK_BLOCKS) do the adjacency atomicExch build instead.
// mode: 0=none, 1=out = staged@WfT + bias, 2=out += staged@WfT.

__global__ __launch_bounds__(256) void k_gemm(const float* __restrict__ Af32,
                                              const unsigned short* __restrict__ Abf,
                                              const unsigned short* __restrict__ WT,
                                              unsigned short* __restrict__ hl,
                                              const float* __restrict__ sums,
                                              const float* __restrict__ g,
                                              const float* __restrict__ be,
                                              const unsigned short* __restrict__ WfT,
                                              const float* __restrict__ bfv,
                                              float* __restrict__ outp, int mode,
                                              const int* __restrict__ linkEi,
                                              int* __restrict__ head,
                                              int* __restrict__ next) {
    __shared__ unsigned short SM[32768];      // 64 KB: As=SM[0:16384), Ws=SM[16384:32768)
    unsigned short* As = SM;
    unsigned short* Ws = SM + 16384;
    int tid = threadIdx.x;
    int bid = blockIdx.x;

    if (linkEi) {
        if (bid < LINK_BLOCKS) {   // adjacency build: 1 atomic/edge, padded heads
            int e = bid * 256 + tid;              // exactly covers N_EDGES
            int d = linkEi[N_EDGES + e];
            next[e] = atomicExch(&head[d << 4], e);
            return;
        }
        bid -= LINK_BLOCKS;
    }
    int row0 = bid * 128;

    // stage Ws (bf16 W^T [n][k]); XOR swizzle in 16B blocks: 2-way conflicts max (free)
    const ushort4* WT4 = (const ushort4*)WT;
#pragma unroll
    for (int i = 0; i < 16; ++i) {
        int idx = i * 256 + tid;
        int r = idx >> 5, c4 = idx & 31;
        ushort4 v = WT4[idx];
        int swz = (c4 >> 1) ^ (r & 15);
        *(ushort4*)&Ws[r * 128 + swz * 8 + (c4 & 1) * 4] = v;
    }

    if (Abf) {
        // bf16 A path: thread stages 8 fixed columns cc..cc+7 (c8 = tid&15)
        int c8 = tid & 15, cc = c8 * 8;
        float s8[8], t8[8];
#pragma unroll
        for (int u = 0; u < 8; ++u) {
            float mean = sums[cc + u] * (1.0f / N_NODES);
            float var = fmaxf(sums[128 + cc + u] * (1.0f / N_NODES) - mean * mean, 0.f);
            float s = g[cc + u] * rsqrtf(var + BN_EPS);
            s8[u] = s;
            t8[u] = be[cc + u] - mean * s;
        }
        const uint4* H4 = (const uint4*)Abf;
#pragma unroll
        for (int i = 0; i < 8; ++i) {
            int idx = i * 256 + tid;
            int r = idx >> 4;                   // 0..127
            int gr = row0 + r;
            uint4 v = make_uint4(0, 0, 0, 0);
            if (gr < N_NODES) v = H4[(size_t)gr * 16 + c8];
            uint32 w[4] = {v.x, v.y, v.z, v.w};
            uint32 o[4];
#pragma unroll
            for (int p = 0; p < 4; ++p) {
                float f0 = bf2f(w[p] & 0xFFFFu) * s8[2 * p] + t8[2 * p];
                float f1 = bf2f(w[p] >> 16) * s8[2 * p + 1] + t8[2 * p + 1];
                o[p] = pack_bf2(fmaxf(f0, 0.f), fmaxf(f1, 0.f));
            }
            int swz = c8 ^ (r & 15);
            *(uint4*)&As[r * 128 + swz * 8] = make_uint4(o[0], o[1], o[2], o[3]);
        }
    } else {
        // fp32 A path (layer 1: x, no BN)
        const float4* A4 = (const float4*)Af32;
#pragma unroll
        for (int i = 0; i < 16; ++i) {
            int idx = i * 256 + tid;
            int r = idx >> 5, c4 = idx & 31;
            int gr = row0 + r;
            float4 v = make_float4(0.f, 0.f, 0.f, 0.f);
            if (gr < N_NODES) v = A4[(size_t)gr * 32 + c4];
            ushort4 o;
            o.x = (unsigned short)f2bf(v.x);
            o.y = (unsigned short)f2bf(v.y);
            o.z = (unsigned short)f2bf(v.z);
            o.w = (unsigned short)f2bf(v.w);
            int swz = (c4 >> 1) ^ (r & 15);
            *(ushort4*)&As[r * 128 + swz * 8 + (c4 & 1) * 4] = o;
        }
    }
    __syncthreads();

    int wave = tid >> 6, lane = tid & 63;
    int quad = lane >> 4, l16 = lane & 15;
    int m0 = wave * 32;

    // a-frags: A[m=lane&15][k = ks*32 + quad*8 + j]
    bf16x8 af[2][4];
#pragma unroll
    for (int mt = 0; mt < 2; ++mt) {
        int m = m0 + mt * 16 + l16;
#pragma unroll
        for (int ks = 0; ks < 4; ++ks) {
            int swz = (ks * 4 + quad) ^ (m & 15);
            af[mt][ks] = *(bf16x8*)&As[m * 128 + swz * 8];
        }
    }

    f32x4 acc[8][2];
#pragma unroll
    for (int nt = 0; nt < 8; ++nt)
#pragma unroll
        for (int mt = 0; mt < 2; ++mt) acc[nt][mt] = (f32x4){0.f, 0.f, 0.f, 0.f};

#pragma unroll
    for (int nt = 0; nt < 8; ++nt) {
        int n = nt * 16 + l16;
        bf16x8 bfr[4];
#pragma unroll
        for (int ks = 0; ks < 4; ++ks) {
            int swz = (ks * 4 + quad) ^ (n & 15);
            bfr[ks] = *(bf16x8*)&Ws[n * 128 + swz * 8];
        }
#pragma unroll
        for (int mt = 0; mt < 2; ++mt)
#pragma unroll
            for (int ks = 0; ks < 4; ++ks)
                acc[nt][mt] = __builtin_amdgcn_mfma_f32_16x16x32_bf16(
                    af[mt][ks], bfr[ks], acc[nt][mt], 0, 0, 0);
    }

    // fused readout partial: out (=|+=) staged @ WfT (+bias). 8 extra MFMAs.
    if (mode != 0) {
        f32x4 accO[2] = {(f32x4){0.f, 0.f, 0.f, 0.f}, (f32x4){0.f, 0.f, 0.f, 0.f}};
#pragma unroll
        for (int ks = 0; ks < 4; ++ks) {
            int chunk = ks * 4 + quad;
            bf16x8 bw = *(const bf16x8*)&WfT[l16 * 128 + chunk * 8];  // tiny, L2-hot
            accO[0] = __builtin_amdgcn_mfma_f32_16x16x32_bf16(af[0][ks], bw, accO[0], 0, 0, 0);
            accO[1] = __builtin_amdgcn_mfma_f32_16x16x32_bf16(af[1][ks], bw, accO[1], 0, 0, 0);
        }
        if (l16 < C_OUT) {
#pragma unroll
            for (int mt = 0; mt < 2; ++mt)
#pragma unroll
                for (int reg = 0; reg < 4; ++reg) {
                    int m = row0 + m0 + mt * 16 + quad * 4 + reg;
                    if (m < N_NODES) {
                        size_t o = (size_t)m * C_OUT + l16;
                        float v = accO[mt][reg];
                        if (mode == 1) outp[o] = v + bfv[l16];
                        else outp[o] += v;
                    }
                }
        }
    }

    // C-tile: acc -> LDS bf16 -> coalesced uint4 stores
    __syncthreads();   // all waves done reading As/Ws
#pragma unroll
    for (int mt = 0; mt < 2; ++mt) {
#pragma unroll
        for (int reg = 0; reg < 4; ++reg) {
            int lm = m0 + mt * 16 + quad * 4 + reg;    // local row 0..127
#pragma unroll
            for (int nt = 0; nt < 8; ++nt)
                SM[lm * CSTR + nt * 16 + l16] = (unsigned short)f2bf(acc[nt][mt][reg]);
        }
    }
    __syncthreads();
    uint4* H4o = (uint4*)hl;
#pragma unroll
    for (int i = 0; i < 8; ++i) {
        int idx = i * 256 + tid;
        int r = idx >> 4, c8 = idx & 15;
        int gr = row0 + r;
        if (gr < N_NODES)
            H4o[(size_t)gr * 16 + c8] = *(uint4*)&SM[r * CSTR + c8 * 8];
    }
}

// ---------------- Aggregation: wave/node, unroll-8, per-edge dinv ----------------

__global__ void k_agg(const unsigned short* __restrict__ hl, const int* __restrict__ adj,
                      const int* __restrict__ cnt, const float* __restrict__ dinv,
                      unsigned short* __restrict__ agg) {
    int node = (int)((blockIdx.x * blockDim.x + threadIdx.x) >> 6);
    int lane = threadIdx.x & 63;
    if (node >= N_NODES) return;
    const int* row = adj + ((size_t)node << 6);   // wave-uniform scalar reads
    int n = cnt[node];
    float ax = 0.f, ay = 0.f;
    int e = 0;
    for (; e + 7 < n; e += 8) {
        int j[8];
#pragma unroll
        for (int u = 0; u < 8; ++u) j[u] = row[e + u];
        float w[8];
        uint32 p[8];
#pragma unroll
        for (int u = 0; u < 8; ++u) {
            w[u] = dinv[j[u]];
            p[u] = *(const uint32*)&hl[(size_t)j[u] * 128 + lane * 2];
        }
#pragma unroll
        for (int u = 0; u < 8; ++u) {
            ax += bf2f(p[u] & 0xFFFFu) * w[u];
            ay += bf2f(p[u] >> 16) * w[u];
        }
    }
    for (; e < n; ++e) {
        int j = row[e];
        float w = dinv[j];
        uint32 p = *(const uint32*)&hl[(size_t)j * 128 + lane * 2];
        ax += bf2f(p & 0xFFFFu) * w;
        ay += bf2f(p >> 16) * w;
    }
    float di = dinv[node];
    *(uint32*)&agg[(size_t)node * 128 + lane * 2] = pack_bf2(ax * di, ay * di);
}

// ---------------- BN stats over bf16 agg (uint32/lane, 4-wave LDS reduce) ----------------

__global__ __launch_bounds__(256) void k_bn_stats(const unsigned short* __restrict__ agg,
                                                  float* __restrict__ sums) {
    __shared__ float red[4][256];
    int tid = threadIdx.x;
    int lane = tid & 63, w = tid >> 6;
    float sx = 0.f, qx = 0.f, sy = 0.f, qy = 0.f;
    for (int r = blockIdx.x * 4 + w; r < N_NODES; r += gridDim.x * 4) {
        uint32 p = *(const uint32*)&agg[(size_t)r * 128 + lane * 2];
        float x = bf2f(p & 0xFFFFu), y = bf2f(p >> 16);
        sx += x; qx += x * x; sy += y; qy += y * y;
    }
    red[0][tid] = sx; red[1][tid] = qx; red[2][tid] = sy; red[3][tid] = qy;
    __syncthreads();
    int s = tid >> 6, l = tid & 63;
    float v = red[s][l] + red[s][64 + l] + red[s][128 + l] + red[s][192 + l];
    atomicAdd(&sums[(s & 1) * 128 + 2 * l + (s >> 1)], v);
}

// ---------------- Layer-3 readout: MFMA, out += bnrelu(h3) @ WfT-slice2 ----------------

__global__ __launch_bounds__(256) void k_out_mfma(const unsigned short* __restrict__ h,
                                                  const unsigned short* __restrict__ WfT,
                                                  float* __restrict__ outp,
                                                  const float* __restrict__ sums,
                                                  const float* __restrict__ g,
                                                  const float* __restrict__ be) {
    __shared__ unsigned short As[128 * 128];  // 32 KB
    int tid = threadIdx.x;
    int row0 = blockIdx.x * 128;

    int c8 = tid & 15, cc = c8 * 8;
    float s8[8], t8[8];
#pragma unroll
    for (int u = 0; u < 8; ++u) {
        float mean = sums[cc + u] * (1.0f / N_NODES);
        float var = fmaxf(sums[128 + cc + u] * (1.0f / N_NODES) - mean * mean, 0.f);
        float s = g[cc + u] * rsqrtf(var + BN_EPS);
        s8[u] = s;
        t8[u] = be[cc + u] - mean * s;
    }
    const uint4* H4 = (const uint4*)h;
#pragma unroll
    for (int i = 0; i < 8; ++i) {
        int idx = i * 256 + tid;
        int r = idx >> 4;
        int gr = row0 + r;
        uint4 v = make_uint4(0, 0, 0, 0);
        if (gr < N_NODES) v = H4[(size_t)gr * 16 + c8];
        uint32 w[4] = {v.x, v.y, v.z, v.w};
        uint32 o[4];
#pragma unroll
        for (int p = 0; p < 4; ++p) {
            float f0 = bf2f(w[p] & 0xFFFFu) * s8[2 * p] + t8[2 * p];
            float f1 = bf2f(w[p] >> 16) * s8[2 * p + 1] + t8[2 * p + 1];
            o[p] = pack_bf2(fmaxf(f0, 0.f), fmaxf(f1, 0.f));
        }
        int swz = c8 ^ (r & 15);
        *(uint4*)&As[r * 128 + swz * 8] = make_uint4(o[0], o[1], o[2], o[3]);
    }
    __syncthreads();

    int wave = tid >> 6, lane = tid & 63;
    int quad = lane >> 4, l16 = lane & 15;
    int m0 = wave * 32;

    f32x4 accO[2] = {(f32x4){0.f, 0.f, 0.f, 0.f}, (f32x4){0.f, 0.f, 0.f, 0.f}};
#pragma unroll
    for (int ks = 0; ks < 4; ++ks) {
        bf16x8 bw = *(const bf16x8*)&WfT[l16 * 128 + (ks * 4 + quad) * 8];
#pragma unroll
        for (int mt = 0; mt < 2; ++mt) {
            int m = m0 + mt * 16 + l16;
            int swz = (ks * 4 + quad) ^ (m & 15);
            bf16x8 av = *(bf16x8*)&As[m * 128 + swz * 8];
            accO[mt] = __builtin_amdgcn_mfma_f32_16x16x32_bf16(av, bw, accO[mt], 0, 0, 0);
        }
    }
    if (l16 < C_OUT) {
#pragma unroll
        for (int mt = 0; mt < 2; ++mt)
#pragma unroll
            for (int reg = 0; reg < 4; ++reg) {
                int m = row0 + m0 + mt * 16 + quad * 4 + reg;
                if (m < N_NODES)
                    outp[(size_t)m * C_OUT + l16] += accO[mt][reg];
            }
    }
}

// ---------------- launch ----------------

extern "C" void kernel_launch(void* const* d_in, const int* in_sizes, int n_in,
                              void* d_out, int out_size, void* d_ws, size_t ws_size,
                              hipStream_t stream) {
    const float* x  = (const float*)d_in[0];
    const int*   ei = (const int*)d_in[1];
    const float* W1 = (const float*)d_in[2];
    const float* W2 = (const float*)d_in[4];
    const float* W3 = (const float*)d_in[6];
    // b1/b2/b3 absorbed exactly by BN mean-subtraction
    const float* g1  = (const float*)d_in[8];
    const float* be1 = (const float*)d_in[9];
    const float* g2  = (const float*)d_in[10];
    const float* be2 = (const float*)d_in[11];
    const float* g3  = (const float*)d_in[12];
    const float* be3 = (const float*)d_in[13];
    const float* Wf  = (const float*)d_in[14];
    const float* bf  = (const float*)d_in[15];
    float* out = (float*)d_out;

    char* ws = (char*)d_ws;
    size_t off = 0;
    auto alloc = [&](size_t bytes) -> void* {
        void* p = ws + off;
        off = (off + bytes + 255) & ~(size_t)255;
        return p;
    };
    int*   head  = (int*)alloc((size_t)N_NODES * 16 * 4);    // 64B-padded heads, 3.2MB
    int*   next  = (int*)alloc((size_t)N_EDGES * 4);
    int*   adj   = (int*)alloc((size_t)N_NODES * CAP * 4);   // 12.8 MB padded rows
    int*   cnt   = (int*)alloc((size_t)N_NODES * 4);
    float* dinv  = (float*)alloc((size_t)N_NODES * 4);
    float* sums  = (float*)alloc(768 * 4);
    unsigned short* WT   = (unsigned short*)alloc((size_t)3 * 128 * 128 * 2);
    unsigned short* WfT  = (unsigned short*)alloc((size_t)3 * 16 * 128 * 2);
    unsigned short* hl   = (unsigned short*)alloc((size_t)N_NODES * 128 * 2);  // bf16
    unsigned short* bufA = (unsigned short*)alloc((size_t)N_NODES * 128 * 2);  // bf16 agg
    // bufB eliminated: hl <-> bufA ping-pong (hl dead after agg_l, bufA dead
    // after gemm_{l+1}); 12.8 MB less workspace touched per replay.

    const int TPB = 256;
    k_setup<<<412, 256, 0, stream>>>(W1, W2, W3, Wf, WT, WfT, head, sums);

    const int agg_grid = (N_NODES + 3) / 4;            // wave per node, 4/block

    // ---- layer 1 GEMM fused with adjacency link build (independent work) ----
    k_gemm<<<LINK_BLOCKS + GEMM_GRID, 256, 0, stream>>>(
        x, nullptr, WT, hl, nullptr, nullptr, nullptr,
        nullptr, nullptr, nullptr, 0, ei, head, next);
    k_walk<<<(N_NODES + TPB - 1) / TPB, TPB, 0, stream>>>(ei, head, next, adj, cnt, dinv);
    k_agg<<<agg_grid, 256, 0, stream>>>(hl, adj, cnt, dinv, bufA);
    k_bn_stats<<<512, 256, 0, stream>>>(bufA, sums + 0);

    // ---- layer 2 (gemm also emits out = h1 @ Wf0 + bf) ----
    k_gemm<<<GEMM_GRID, 256, 0, stream>>>(nullptr, bufA, WT + 16384, hl, sums + 0, g1, be1,
                                          WfT, bf, out, 1, nullptr, nullptr, nullptr);
    k_agg<<<agg_grid, 256, 0, stream>>>(hl, adj, cnt, dinv, bufA);
    k_bn_stats<<<512, 256, 0, stream>>>(bufA, sums + 256);

    // ---- layer 3 (gemm also emits out += h2 @ Wf1) ----
    k_gemm<<<GEMM_GRID, 256, 0, stream>>>(nullptr, bufA, WT + 32768, hl, sums + 256, g2, be2,
                                          WfT + 2048, nullptr, out, 2, nullptr, nullptr, nullptr);
    k_agg<<<agg_grid, 256, 0, stream>>>(hl, adj, cnt, dinv, bufA);
    k_bn_stats<<<512, 256, 0, stream>>>(bufA, sums + 512);

    // ---- layer 3 readout (MFMA) ----
    k_out_mfma<<<GEMM_GRID, 256, 0, stream>>>(bufA, WfT + 4096, out, sums + 512, g3, be3);
}